// Round 5
// baseline (151.232 us; speedup 1.0000x reference)
//
#include <hip/hip_runtime.h>
#include <hip/hip_bf16.h>
#include <math.h>

// Contrastive (NT-Xent-like) loss over x[16384][64] fp32.
//   x_hat = sqrt(2*log2e) * x / ||x||   (so exp(sim/T) = exp2(x_hat_i.x_hat_j))
//   den[j] = sum_i exp2(x_hat_i . x_hat_j) - e^2
//   num[j] = exp2(x_hat_{j^1} . x_hat_j)
//   out = -log( mean_j num[j] / den[j] )
//
// Round 19: r18 never ran (GPU broker timeout) — resubmitting byte-identical.
// r18 rationale: r17's acc double-buffer spilled (WRITE 105 MB scratch, den
// 84). Lesson: never hold 2x64-reg acc across barriers. r16's counters
// (nothing saturated) say the real cost is PER-PAIR OVERHEAD x 8256 pairs
// (2 barriers, 32 KB stage, 18-shfl butterflies, LDS combine, stores per 16K
// elements); the exp2 core is only ~10-14 us chip-wide.
// AMORTIZE: 256x256 tile-pairs (2080 one-shot blocks), processed as 4x
// 128x128 quadrants reusing ONE 64-reg acc (short live range, no
// cross-barrier acc state). Col/row partials accumulate across quadrants in
// registers (8+32 floats); butterflies + red combine + barriers + S-stores
// run once per 65K elements (4x amortized); staged bytes/element halved;
// S shrinks 8->4 MB. Per-element math byte-identical to r13-r16.
// LDS 68 KB -> 2 blocks/CU; launch_bounds(256,2).
// Success: den 30-36 us, total 85-92, no WRITE_SIZE jump.
// Failure A: wrong result -> quadrant/num/red mapping bug -> revert r14.
// Failure B: WRITE_SIZE >> 50 MB -> spill -> drop min-waves bound.
// Failure C: den >=44 -> overhead wasn't the cost -> attack exp2/trans chain.

#define NROWS 16384
#define KDIM 64
#define TILE2 256
#define NTB2 (NROWS / TILE2)            // 64 tile-blocks per side
#define NPAIRS2 (NTB2 * (NTB2 + 1) / 2) // 2080 upper-triangle tile pairs

typedef __attribute__((ext_vector_type(8))) short short8;   // 8 bf16 = 4 VGPRs
typedef __attribute__((ext_vector_type(4))) float f32x4;
typedef __attribute__((ext_vector_type(2))) float f32x2;

__device__ __forceinline__ float exp2_fast(float x) {
#if __has_builtin(__builtin_amdgcn_exp2f)
    return __builtin_amdgcn_exp2f(x);   // bare v_exp_f32
#else
    return exp2f(x);
#endif
}

// async global->LDS DMA, 16 B per lane; LDS side must be uniform + lane*16.
__device__ __forceinline__ void load_lds16(const void* g, void* l) {
    __builtin_amdgcn_global_load_lds((const __attribute__((address_space(1))) unsigned int*)g,
                                     (__attribute__((address_space(3))) unsigned int*)l,
                                     16, 0, 0);
}

// ---- kernel A: row-normalize, prescale by sqrt(2*log2e) -> bf16 -----------
// 64 rows/block, 4 lanes/row, 16 floats/thread. Also zeroes ctrl/accum.
__global__ __launch_bounds__(256) void normalize_kernel(const float* __restrict__ x,
                                                        unsigned short* __restrict__ xnb,
                                                        unsigned int* __restrict__ ctrl,
                                                        float* __restrict__ accum) {
    const int t = threadIdx.x;
    const int r = blockIdx.x * 64 + (t >> 2);
    const int q = t & 3;
    const float4* xr = (const float4*)(x + (size_t)r * KDIM) + q * 4;
    const float4 v0 = xr[0], v1 = xr[1], v2 = xr[2], v3 = xr[3];
    float ss = v0.x * v0.x + v0.y * v0.y + v0.z * v0.z + v0.w * v0.w
             + v1.x * v1.x + v1.y * v1.y + v1.z * v1.z + v1.w * v1.w
             + v2.x * v2.x + v2.y * v2.y + v2.z * v2.z + v2.w * v2.w
             + v3.x * v3.x + v3.y * v3.y + v3.z * v3.z + v3.w * v3.w;
    ss += __shfl_xor(ss, 1, 64);
    ss += __shfl_xor(ss, 2, 64);
    // sqrt(2*log2(e)) = sqrt(2.88539008) = 1.69864404
    const float a = 1.69864404f * rsqrtf(fmaxf(ss, 1e-16f));
    const float vals[16] = {v0.x * a, v0.y * a, v0.z * a, v0.w * a,
                            v1.x * a, v1.y * a, v1.z * a, v1.w * a,
                            v2.x * a, v2.y * a, v2.z * a, v2.w * a,
                            v3.x * a, v3.y * a, v3.z * a, v3.w * a};
    union { unsigned short us[16]; uint4 v[2]; } o;
    #pragma unroll
    for (int k = 0; k < 16; k++) {
        __hip_bfloat16 b = __float2bfloat16(vals[k]);
        o.us[k] = *(unsigned short*)&b;
    }
    uint4* dst = (uint4*)(xnb + (size_t)r * KDIM);
    dst[q * 2] = o.v[0];
    dst[q * 2 + 1] = o.v[1];
    if (blockIdx.x == 0 && t == 0) { ctrl[0] = 0u; ctrl[1] = 0u; accum[0] = 0.0f; }
}

// ---- kernel B: 256x256 tile-pair partial sums (4 quadrants in registers) --
// Block = upper-triangle 256-tile pair (ti<=tj), one-shot, 2080 blocks.
// 4 waves 2x2 per 128x128 quadrant; mfma_f32_16x16x32_bf16 (A-frag: lane
// m=l&15 holds k=(l>>4)*8+e; C/D: col=l&15, row=(l>>4)*4+reg). Both tiles
// (256 rows x 64 bf16 each) staged via global_load_lds width=16, XOR-swizzled
// chunk(r,q) at r*8 + (q^(r&7)): coalesced staging, 0 bank conflicts
// (r3-r13-verified layout; row offsets qi*128 preserve r&7). 68 KB LDS.
__global__ __launch_bounds__(256, 2) void den_kernel(const unsigned short* __restrict__ xnb,
                                                     float* __restrict__ S,
                                                     float* __restrict__ num) {
    __shared__ float4 Abuf[2048];  // 32 KB: 256 rows x 128 B
    __shared__ float4 Bbuf[2048];  // 32 KB
    __shared__ float red[1024];    // 4 KB cross-wave combine scratch

    const int t = threadIdx.x;
    const int bt = blockIdx.x;
    // triangular decode (f32; loops absorb rounding): bt -> (ti, tj), NTB2=64
    int ti = (int)((129.0f - sqrtf(16641.0f - 8.0f * (float)bt)) * 0.5f);
    while (ti * NTB2 - ti * (ti - 1) / 2 > bt) ti--;
    while ((ti + 1) * NTB2 - (ti + 1) * ti / 2 <= bt) ti++;
    const int tj = ti + (bt - (ti * NTB2 - ti * (ti - 1) / 2));
    const int ib = ti * TILE2, jb = tj * TILE2;
    const bool diag = (ti == tj);

    // staging: chunk c -> row r=c>>3, k-chunk q=(c&7)^(r&7). Global side is a
    // per-lane VGPR address (swizzle allowed); LDS side is uniform + lane*16.
    #pragma unroll
    for (int s = 0; s < 8; s++) {
        const int c = s * 256 + t;
        const int r = c >> 3;
        const int q = ((c & 7) ^ (r & 7)) * 8;
        load_lds16(xnb + (size_t)(ib + r) * KDIM + q, &Abuf[c]);
        load_lds16(xnb + (size_t)(jb + r) * KDIM + q, &Bbuf[c]);
    }
    __syncthreads();   // compiler drains vmcnt before s_barrier (covers DMA)

    const int lane = t & 63, w = t >> 6;
    const int wi = w >> 1, wj = w & 1;
    const int m = lane & 15, p = lane >> 4;

    // cross-quadrant accumulators (pre-butterfly partials)
    f32x2 cs01[2], cs23[2];   // per qj: col partials
    float rsq[2][16];         // per qi: row partials
    #pragma unroll
    for (int q2 = 0; q2 < 2; q2++) {
        cs01[q2].x = 0.f; cs01[q2].y = 0.f;
        cs23[q2].x = 0.f; cs23[q2].y = 0.f;
        #pragma unroll
        for (int k = 0; k < 16; k++) rsq[q2][k] = 0.f;
    }

    const f32x4 zero = {0.f, 0.f, 0.f, 0.f};
    const unsigned short* As = (const unsigned short*)Abuf;
    const unsigned short* Bs = (const unsigned short*)Bbuf;

    #pragma unroll
    for (int qi = 0; qi < 2; qi++) {
        #pragma unroll
        for (int qj = 0; qj < 2; qj++) {
            f32x4 acc[4][4];
            #pragma unroll
            for (int it = 0; it < 4; it++)
                #pragma unroll
                for (int jt = 0; jt < 4; jt++) acc[it][jt] = zero;

            #pragma unroll
            for (int kc = 0; kc < 2; kc++) {
                short8 af[4], bf[4];
                const int qx = ((kc << 2) | p) ^ (m & 7);
                #pragma unroll
                for (int it = 0; it < 4; it++) {
                    af[it] = *(const short8*)(As + ((qi * 128 + wi * 64 + it * 16 + m) * 8 + qx) * 8);
                    bf[it] = *(const short8*)(Bs + ((qj * 128 + wj * 64 + it * 16 + m) * 8 + qx) * 8);
                }
                #pragma unroll
                for (int it = 0; it < 4; it++)
                    #pragma unroll
                    for (int jt = 0; jt < 4; jt++)
                        acc[it][jt] = __builtin_amdgcn_mfma_f32_16x16x32_bf16(af[it], bf[jt], acc[it][jt], 0, 0, 0);
            }

            // epilogue: exp2; packed accumulation into cross-quadrant partials
            #pragma unroll
            for (int it = 0; it < 4; it++) {
                #pragma unroll
                for (int reg = 0; reg < 4; reg++) {
                    f32x2 e01, e23;
                    e01.x = exp2_fast(acc[it][0][reg]);
                    e01.y = exp2_fast(acc[it][1][reg]);
                    e23.x = exp2_fast(acc[it][2][reg]);
                    e23.y = exp2_fast(acc[it][3][reg]);
                    cs01[qj] += e01;
                    cs23[qj] += e23;
                    const f32x2 rp = e01 + e23;
                    rsq[qi][it * 4 + reg] += rp.x + rp.y;
                }
            }

            // num[j] = exp2(acc(row j^1, col j)) from diagonal 128-sub-blocks:
            // element (m^1, m) of sub-tile it lives in lane ((m^1)>>2, m),
            // reg (m^1)&3. Needs qi==qj (diag quadrant) and wi==wj.
            if (diag && qi == qj && wi == wj) {
                const int pc = m ^ 1;
                if ((pc >> 2) == p) {
                    #pragma unroll
                    for (int it = 0; it < 4; it++)
                        num[jb + qj * 128 + wj * 64 + it * 16 + m] = exp2_fast(acc[it][it][pc & 3]);
                }
            }
        }
    }

    // colsum butterflies per qj (value-halving over p): lane ends with column
    // (within quadrant-wave) p*16+m; full col = qj*128 + wj*64 + p*16 + m.
    #pragma unroll
    for (int qj = 0; qj < 2; qj++) {
        float cs[4] = {cs01[qj].x, cs01[qj].y, cs23[qj].x, cs23[qj].y};
        const bool hb = (p & 2) != 0;
        float s0 = hb ? cs[0] : cs[2], k0 = hb ? cs[2] : cs[0];
        float s1 = hb ? cs[1] : cs[3], k1 = hb ? cs[3] : cs[1];
        cs[0] = k0 + __shfl_xor(s0, 32, 64);
        cs[1] = k1 + __shfl_xor(s1, 32, 64);
        const bool lb = (p & 1) != 0;
        float s2 = lb ? cs[0] : cs[1], k2 = lb ? cs[1] : cs[0];
        cs[0] = k2 + __shfl_xor(s2, 16, 64);
        red[wi * 256 + qj * 128 + wj * 64 + p * 16 + m] = cs[0];
    }

    // rowsum butterflies per qi (value-halving over m, 15 shfl): lane ends
    // with row-in-wave (m>>2)*16 + p*4 + (m&3); full row = qi*128 + wi*64 + rw.
    if (!diag) {
        #pragma unroll
        for (int qi = 0; qi < 2; qi++) {
            float rs[16];
            #pragma unroll
            for (int k = 0; k < 16; k++) rs[k] = rsq[qi][k];
            #pragma unroll
            for (int k = 0; k < 8; k++) {
                const float snd = (m & 8) ? rs[k] : rs[k + 8];
                const float kp  = (m & 8) ? rs[k + 8] : rs[k];
                rs[k] = kp + __shfl_xor(snd, 8, 64);
            }
            #pragma unroll
            for (int k = 0; k < 4; k++) {
                const float snd = (m & 4) ? rs[k] : rs[k + 4];
                const float kp  = (m & 4) ? rs[k + 4] : rs[k];
                rs[k] = kp + __shfl_xor(snd, 4, 64);
            }
            #pragma unroll
            for (int k = 0; k < 2; k++) {
                const float snd = (m & 2) ? rs[k] : rs[k + 2];
                const float kp  = (m & 2) ? rs[k + 2] : rs[k];
                rs[k] = kp + __shfl_xor(snd, 2, 64);
            }
            {
                const float snd = (m & 1) ? rs[0] : rs[1];
                const float kp  = (m & 1) ? rs[1] : rs[0];
                rs[0] = kp + __shfl_xor(snd, 1, 64);
            }
            red[512 + wj * 256 + qi * 128 + wi * 64 + ((m >> 2) * 16 + p * 4 + (m & 3))] = rs[0];
        }
    }
    __syncthreads();

    // exactly-once coalesced partial stores (no atomics, no fences):
    //   colsums -> S[tj][ti][c] (den[jb+c]); rowsums -> S[ti][tj][r] (den[ib+r])
    S[((size_t)tj * NTB2 + ti) * TILE2 + t] = red[t] + red[256 + t];
    if (!diag)
        S[((size_t)ti * NTB2 + tj) * TILE2 + t] = red[512 + t] + red[768 + t];
}

// ---- kernel C: den[a*256+c] = sum_b S[a][b][c]; ratio + global sum + log ---
// 64 blocks x 256 threads; ticket write of the final scalar (r6-verified).
__global__ __launch_bounds__(256) void reduce_kernel(const float* __restrict__ S,
                                                     const float* __restrict__ num,
                                                     unsigned int* __restrict__ ctrl,
                                                     float* __restrict__ accum,
                                                     float* __restrict__ out) {
    const int a = blockIdx.x;
    const int t = threadIdx.x;   // c = t in [0,256)
    const float* base = S + (size_t)a * (NTB2 * TILE2) + t;
    float s = 0.0f;
    #pragma unroll 8
    for (int b = 0; b < NTB2; b++) s += base[(size_t)b * TILE2];

    const float E2 = 7.38905609893065f;  // exp(1/T)=exp(2): diagonal removal
    float r = num[a * TILE2 + t] / (s - E2);

    #pragma unroll
    for (int o = 32; o > 0; o >>= 1) r += __shfl_xor(r, o, 64);
    __shared__ float wsum[4];
    if ((t & 63) == 0) wsum[t >> 6] = r;
    __syncthreads();
    if (t == 0) {
        const float bsum = (wsum[0] + wsum[1]) + (wsum[2] + wsum[3]);
        __hip_atomic_fetch_add(accum, bsum, __ATOMIC_RELAXED, __HIP_MEMORY_SCOPE_AGENT);
        const unsigned int tk = __hip_atomic_fetch_add(&ctrl[1], 1u, __ATOMIC_ACQ_REL, __HIP_MEMORY_SCOPE_AGENT);
        if (tk == (unsigned)(NTB2 - 1)) {   // last block writes the loss
            const float total = __hip_atomic_load(accum, __ATOMIC_ACQUIRE, __HIP_MEMORY_SCOPE_AGENT);
            out[0] = -logf(total / (float)NROWS);
        }
    }
}

extern "C" void kernel_launch(void* const* d_in, const int* in_sizes, int n_in,
                              void* d_out, int out_size, void* d_ws, size_t ws_size,
                              hipStream_t stream) {
    const float* x = (const float*)d_in[0];
    float* out = (float*)d_out;

    // ws: xnb [2 MB bf16] | num [64 KB f32] | accum [1 f32] | ctrl [2 u32] | S [4 MB f32]
    unsigned short* xnb = (unsigned short*)d_ws;
    float* num = (float*)((char*)d_ws + (size_t)NROWS * KDIM * sizeof(unsigned short));
    float* accum = num + NROWS;
    unsigned int* ctrl = (unsigned int*)(accum + 1);
    float* S = (float*)(ctrl + 2);

    normalize_kernel<<<NROWS / 64, 256, 0, stream>>>(x, xnb, ctrl, accum);
    den_kernel<<<NPAIRS2, 256, 0, stream>>>(xnb, S, num);
    reduce_kernel<<<NTB2, 256, 0, stream>>>(S, num, ctrl, accum, out);
}

// Round 6
// 114.380 us; speedup vs baseline: 1.3222x; 1.3222x over previous
//
#include <hip/hip_runtime.h>
#include <hip/hip_bf16.h>
#include <math.h>

// Contrastive (NT-Xent-like) loss over x[16384][64] fp32.
//   x_hat = sqrt(2*log2e) * x / ||x||   (so exp(sim/T) = exp2(x_hat_i.x_hat_j))
//   den[j] = sum_i exp2(x_hat_i . x_hat_j) - e^2
//   num[j] = exp2(x_hat_{j^1} . x_hat_j)
//   out = -log( mean_j num[j] / den[j] )
//
// Round 20: r18 post-mortem — 256x256 4-quadrant kernel SPILLED (WRITE 223 MB
// scratch, VGPR pinned 128, den 94). Empirical toolchain fact (r16/r17/r18):
// __launch_bounds__(256,2) caps the allocator at 128 VGPRs; the quadrant
// working set needs ~165. The amortization theory was never tested — r18
// measured pure spill.
// This round, spill-targeted fixes only (structure otherwise r18-identical):
//   1. __launch_bounds__(256) — no min-waves bound. Allocator free to ~200
//      VGPR; <=256 VGPR still gives 2 waves/SIMD = 8 waves/CU = the same
//      2 blocks/CU the 68 KB LDS permits. Occupancy unchanged, spill gone.
//   2. rsq[16] made local to the qi iteration; its rowsum butterfly runs
//      right after the inner qj loop (row partials only accumulate over qj).
//      -16 live VGPRs; peak live ~140-160.
// Success: VGPR 160-200, WRITE ~4.5 MB, FETCH ~10 MB, den 30-36, total 85-92.
// Failure A: wrong result -> mapping bug -> revert r14.
// Failure C: den 44-48 clean (no spill) -> per-pair overhead was NOT the pole;
//            r13's 45.8 den is a real floor -> revert r14, likely ROOFLINE
//            (fill tax 44 us is fixed harness cost).

#define NROWS 16384
#define KDIM 64
#define TILE2 256
#define NTB2 (NROWS / TILE2)            // 64 tile-blocks per side
#define NPAIRS2 (NTB2 * (NTB2 + 1) / 2) // 2080 upper-triangle tile pairs

typedef __attribute__((ext_vector_type(8))) short short8;   // 8 bf16 = 4 VGPRs
typedef __attribute__((ext_vector_type(4))) float f32x4;
typedef __attribute__((ext_vector_type(2))) float f32x2;

__device__ __forceinline__ float exp2_fast(float x) {
#if __has_builtin(__builtin_amdgcn_exp2f)
    return __builtin_amdgcn_exp2f(x);   // bare v_exp_f32
#else
    return exp2f(x);
#endif
}

// async global->LDS DMA, 16 B per lane; LDS side must be uniform + lane*16.
__device__ __forceinline__ void load_lds16(const void* g, void* l) {
    __builtin_amdgcn_global_load_lds((const __attribute__((address_space(1))) unsigned int*)g,
                                     (__attribute__((address_space(3))) unsigned int*)l,
                                     16, 0, 0);
}

// ---- kernel A: row-normalize, prescale by sqrt(2*log2e) -> bf16 -----------
// 64 rows/block, 4 lanes/row, 16 floats/thread. Also zeroes ctrl/accum.
__global__ __launch_bounds__(256) void normalize_kernel(const float* __restrict__ x,
                                                        unsigned short* __restrict__ xnb,
                                                        unsigned int* __restrict__ ctrl,
                                                        float* __restrict__ accum) {
    const int t = threadIdx.x;
    const int r = blockIdx.x * 64 + (t >> 2);
    const int q = t & 3;
    const float4* xr = (const float4*)(x + (size_t)r * KDIM) + q * 4;
    const float4 v0 = xr[0], v1 = xr[1], v2 = xr[2], v3 = xr[3];
    float ss = v0.x * v0.x + v0.y * v0.y + v0.z * v0.z + v0.w * v0.w
             + v1.x * v1.x + v1.y * v1.y + v1.z * v1.z + v1.w * v1.w
             + v2.x * v2.x + v2.y * v2.y + v2.z * v2.z + v2.w * v2.w
             + v3.x * v3.x + v3.y * v3.y + v3.z * v3.z + v3.w * v3.w;
    ss += __shfl_xor(ss, 1, 64);
    ss += __shfl_xor(ss, 2, 64);
    // sqrt(2*log2(e)) = sqrt(2.88539008) = 1.69864404
    const float a = 1.69864404f * rsqrtf(fmaxf(ss, 1e-16f));
    const float vals[16] = {v0.x * a, v0.y * a, v0.z * a, v0.w * a,
                            v1.x * a, v1.y * a, v1.z * a, v1.w * a,
                            v2.x * a, v2.y * a, v2.z * a, v2.w * a,
                            v3.x * a, v3.y * a, v3.z * a, v3.w * a};
    union { unsigned short us[16]; uint4 v[2]; } o;
    #pragma unroll
    for (int k = 0; k < 16; k++) {
        __hip_bfloat16 b = __float2bfloat16(vals[k]);
        o.us[k] = *(unsigned short*)&b;
    }
    uint4* dst = (uint4*)(xnb + (size_t)r * KDIM);
    dst[q * 2] = o.v[0];
    dst[q * 2 + 1] = o.v[1];
    if (blockIdx.x == 0 && t == 0) { ctrl[0] = 0u; ctrl[1] = 0u; accum[0] = 0.0f; }
}

// ---- kernel B: 256x256 tile-pair partial sums (4 quadrants in registers) --
// Block = upper-triangle 256-tile pair (ti<=tj), one-shot, 2080 blocks.
// 4 waves 2x2 per 128x128 quadrant; mfma_f32_16x16x32_bf16 (A-frag: lane
// m=l&15 holds k=(l>>4)*8+e; C/D: col=l&15, row=(l>>4)*4+reg). Both tiles
// (256 rows x 64 bf16 each) staged via global_load_lds width=16, XOR-swizzled
// chunk(r,q) at r*8 + (q^(r&7)): coalesced staging, 0 bank conflicts
// (r3-r13-verified layout; row offsets qi*128 preserve r&7). 68 KB LDS.
// NO min-waves bound (spill avoidance; see header).
__global__ __launch_bounds__(256) void den_kernel(const unsigned short* __restrict__ xnb,
                                                  float* __restrict__ S,
                                                  float* __restrict__ num) {
    __shared__ float4 Abuf[2048];  // 32 KB: 256 rows x 128 B
    __shared__ float4 Bbuf[2048];  // 32 KB
    __shared__ float red[1024];    // 4 KB cross-wave combine scratch

    const int t = threadIdx.x;
    const int bt = blockIdx.x;
    // triangular decode (f32; loops absorb rounding): bt -> (ti, tj), NTB2=64
    int ti = (int)((129.0f - sqrtf(16641.0f - 8.0f * (float)bt)) * 0.5f);
    while (ti * NTB2 - ti * (ti - 1) / 2 > bt) ti--;
    while ((ti + 1) * NTB2 - (ti + 1) * ti / 2 <= bt) ti++;
    const int tj = ti + (bt - (ti * NTB2 - ti * (ti - 1) / 2));
    const int ib = ti * TILE2, jb = tj * TILE2;
    const bool diag = (ti == tj);

    // staging: chunk c -> row r=c>>3, k-chunk q=(c&7)^(r&7). Global side is a
    // per-lane VGPR address (swizzle allowed); LDS side is uniform + lane*16.
    #pragma unroll
    for (int s = 0; s < 8; s++) {
        const int c = s * 256 + t;
        const int r = c >> 3;
        const int q = ((c & 7) ^ (r & 7)) * 8;
        load_lds16(xnb + (size_t)(ib + r) * KDIM + q, &Abuf[c]);
        load_lds16(xnb + (size_t)(jb + r) * KDIM + q, &Bbuf[c]);
    }
    __syncthreads();   // compiler drains vmcnt before s_barrier (covers DMA)

    const int lane = t & 63, w = t >> 6;
    const int wi = w >> 1, wj = w & 1;
    const int m = lane & 15, p = lane >> 4;

    // cross-quadrant col partials (persist over qi; 8 floats)
    f32x2 cs01[2], cs23[2];
    #pragma unroll
    for (int q2 = 0; q2 < 2; q2++) {
        cs01[q2].x = 0.f; cs01[q2].y = 0.f;
        cs23[q2].x = 0.f; cs23[q2].y = 0.f;
    }

    const f32x4 zero = {0.f, 0.f, 0.f, 0.f};
    const unsigned short* As = (const unsigned short*)Abuf;
    const unsigned short* Bs = (const unsigned short*)Bbuf;

    #pragma unroll
    for (int qi = 0; qi < 2; qi++) {
        // row partials local to this qi (accumulate over the inner qj loop)
        float rs[16];
        #pragma unroll
        for (int k = 0; k < 16; k++) rs[k] = 0.f;

        #pragma unroll
        for (int qj = 0; qj < 2; qj++) {
            f32x4 acc[4][4];
            #pragma unroll
            for (int it = 0; it < 4; it++)
                #pragma unroll
                for (int jt = 0; jt < 4; jt++) acc[it][jt] = zero;

            #pragma unroll
            for (int kc = 0; kc < 2; kc++) {
                short8 af[4], bf[4];
                const int qx = ((kc << 2) | p) ^ (m & 7);
                #pragma unroll
                for (int it = 0; it < 4; it++) {
                    af[it] = *(const short8*)(As + ((qi * 128 + wi * 64 + it * 16 + m) * 8 + qx) * 8);
                    bf[it] = *(const short8*)(Bs + ((qj * 128 + wj * 64 + it * 16 + m) * 8 + qx) * 8);
                }
                #pragma unroll
                for (int it = 0; it < 4; it++)
                    #pragma unroll
                    for (int jt = 0; jt < 4; jt++)
                        acc[it][jt] = __builtin_amdgcn_mfma_f32_16x16x32_bf16(af[it], bf[jt], acc[it][jt], 0, 0, 0);
            }

            // epilogue: exp2; packed accumulation into partials
            #pragma unroll
            for (int it = 0; it < 4; it++) {
                #pragma unroll
                for (int reg = 0; reg < 4; reg++) {
                    f32x2 e01, e23;
                    e01.x = exp2_fast(acc[it][0][reg]);
                    e01.y = exp2_fast(acc[it][1][reg]);
                    e23.x = exp2_fast(acc[it][2][reg]);
                    e23.y = exp2_fast(acc[it][3][reg]);
                    cs01[qj] += e01;
                    cs23[qj] += e23;
                    const f32x2 rp = e01 + e23;
                    rs[it * 4 + reg] += rp.x + rp.y;
                }
            }

            // num[j] = exp2(acc(row j^1, col j)) from diagonal 128-sub-blocks:
            // element (m^1, m) of sub-tile it lives in lane ((m^1)>>2, m),
            // reg (m^1)&3. Needs qi==qj (diag quadrant) and wi==wj.
            if (diag && qi == qj && wi == wj) {
                const int pc = m ^ 1;
                if ((pc >> 2) == p) {
                    #pragma unroll
                    for (int it = 0; it < 4; it++)
                        num[jb + qj * 128 + wj * 64 + it * 16 + m] = exp2_fast(acc[it][it][pc & 3]);
                }
            }
        }

        // rowsum butterfly for this qi (value-halving over m, 15 shfl): lane
        // ends with row-in-wave (m>>2)*16+p*4+(m&3); full row = qi*128+wi*64+rw.
        if (!diag) {
            #pragma unroll
            for (int k = 0; k < 8; k++) {
                const float snd = (m & 8) ? rs[k] : rs[k + 8];
                const float kp  = (m & 8) ? rs[k + 8] : rs[k];
                rs[k] = kp + __shfl_xor(snd, 8, 64);
            }
            #pragma unroll
            for (int k = 0; k < 4; k++) {
                const float snd = (m & 4) ? rs[k] : rs[k + 4];
                const float kp  = (m & 4) ? rs[k + 4] : rs[k];
                rs[k] = kp + __shfl_xor(snd, 4, 64);
            }
            #pragma unroll
            for (int k = 0; k < 2; k++) {
                const float snd = (m & 2) ? rs[k] : rs[k + 2];
                const float kp  = (m & 2) ? rs[k + 2] : rs[k];
                rs[k] = kp + __shfl_xor(snd, 2, 64);
            }
            {
                const float snd = (m & 1) ? rs[0] : rs[1];
                const float kp  = (m & 1) ? rs[1] : rs[0];
                rs[0] = kp + __shfl_xor(snd, 1, 64);
            }
            red[512 + wj * 256 + qi * 128 + wi * 64 + ((m >> 2) * 16 + p * 4 + (m & 3))] = rs[0];
        }
    }

    // colsum butterflies per qj (value-halving over p): lane ends with column
    // (within quadrant-wave) p*16+m; full col = qj*128 + wj*64 + p*16 + m.
    #pragma unroll
    for (int qj = 0; qj < 2; qj++) {
        float cs[4] = {cs01[qj].x, cs01[qj].y, cs23[qj].x, cs23[qj].y};
        const bool hb = (p & 2) != 0;
        float s0 = hb ? cs[0] : cs[2], k0 = hb ? cs[2] : cs[0];
        float s1 = hb ? cs[1] : cs[3], k1 = hb ? cs[3] : cs[1];
        cs[0] = k0 + __shfl_xor(s0, 32, 64);
        cs[1] = k1 + __shfl_xor(s1, 32, 64);
        const bool lb = (p & 1) != 0;
        float s2 = lb ? cs[0] : cs[1], k2 = lb ? cs[1] : cs[0];
        cs[0] = k2 + __shfl_xor(s2, 16, 64);
        red[wi * 256 + qj * 128 + wj * 64 + p * 16 + m] = cs[0];
    }
    __syncthreads();

    // exactly-once coalesced partial stores (no atomics, no fences):
    //   colsums -> S[tj][ti][c] (den[jb+c]); rowsums -> S[ti][tj][r] (den[ib+r])
    S[((size_t)tj * NTB2 + ti) * TILE2 + t] = red[t] + red[256 + t];
    if (!diag)
        S[((size_t)ti * NTB2 + tj) * TILE2 + t] = red[512 + t] + red[768 + t];
}

// ---- kernel C: den[a*256+c] = sum_b S[a][b][c]; ratio + global sum + log ---
// 64 blocks x 256 threads; ticket write of the final scalar (r6-verified).
__global__ __launch_bounds__(256) void reduce_kernel(const float* __restrict__ S,
                                                     const float* __restrict__ num,
                                                     unsigned int* __restrict__ ctrl,
                                                     float* __restrict__ accum,
                                                     float* __restrict__ out) {
    const int a = blockIdx.x;
    const int t = threadIdx.x;   // c = t in [0,256)
    const float* base = S + (size_t)a * (NTB2 * TILE2) + t;
    float s = 0.0f;
    #pragma unroll 8
    for (int b = 0; b < NTB2; b++) s += base[(size_t)b * TILE2];

    const float E2 = 7.38905609893065f;  // exp(1/T)=exp(2): diagonal removal
    float r = num[a * TILE2 + t] / (s - E2);

    #pragma unroll
    for (int o = 32; o > 0; o >>= 1) r += __shfl_xor(r, o, 64);
    __shared__ float wsum[4];
    if ((t & 63) == 0) wsum[t >> 6] = r;
    __syncthreads();
    if (t == 0) {
        const float bsum = (wsum[0] + wsum[1]) + (wsum[2] + wsum[3]);
        __hip_atomic_fetch_add(accum, bsum, __ATOMIC_RELAXED, __HIP_MEMORY_SCOPE_AGENT);
        const unsigned int tk = __hip_atomic_fetch_add(&ctrl[1], 1u, __ATOMIC_ACQ_REL, __HIP_MEMORY_SCOPE_AGENT);
        if (tk == (unsigned)(NTB2 - 1)) {   // last block writes the loss
            const float total = __hip_atomic_load(accum, __ATOMIC_ACQUIRE, __HIP_MEMORY_SCOPE_AGENT);
            out[0] = -logf(total / (float)NROWS);
        }
    }
}

extern "C" void kernel_launch(void* const* d_in, const int* in_sizes, int n_in,
                              void* d_out, int out_size, void* d_ws, size_t ws_size,
                              hipStream_t stream) {
    const float* x = (const float*)d_in[0];
    float* out = (float*)d_out;

    // ws: xnb [2 MB bf16] | num [64 KB f32] | accum [1 f32] | ctrl [2 u32] | S [4 MB f32]
    unsigned short* xnb = (unsigned short*)d_ws;
    float* num = (float*)((char*)d_ws + (size_t)NROWS * KDIM * sizeof(unsigned short));
    float* accum = num + NROWS;
    unsigned int* ctrl = (unsigned int*)(accum + 1);
    float* S = (float*)(ctrl + 2);

    normalize_kernel<<<NROWS / 64, 256, 0, stream>>>(x, xnb, ctrl, accum);
    den_kernel<<<NPAIRS2, 256, 0, stream>>>(xnb, S, num);
    reduce_kernel<<<NTB2, 256, 0, stream>>>(S, num, ctrl, accum, out);
}